// Round 4
// baseline (347.714 us; speedup 1.0000x reference)
//
#include <hip/hip_runtime.h>
#include <stdint.h>

#define T_STEPS 256
#define BATCH   2048
#define ISZ     11
#define HID     64
#define PHOR    12

typedef __attribute__((ext_vector_type(8))) short short8;
typedef __attribute__((ext_vector_type(4))) float f32x4;

union S8U { short8 s; uint32_t u[4]; };

__device__ __forceinline__ uint32_t cvt_pk_bf16(float lo, float hi) {
  uint32_t r;
  asm("v_cvt_pk_bf16_f32 %0, %1, %2" : "=v"(r) : "v"(lo), "v"(hi));
  return r;
}
__device__ __forceinline__ float sigm(float v) {
  return __builtin_amdgcn_rcpf(1.0f + __builtin_amdgcn_exp2f(v * -1.44269504f));
}
__device__ __forceinline__ float tanha(float v) {
  return 1.0f - 2.0f * __builtin_amdgcn_rcpf(1.0f + __builtin_amdgcn_exp2f(v * 2.88539008f));
}
// Barrier draining LDS only — global loads stay in flight (no vmcnt(0)).
__device__ __forceinline__ void lds_barrier() {
  asm volatile("s_waitcnt lgkmcnt(0)" ::: "memory");
  __builtin_amdgcn_s_barrier();
  asm volatile("" ::: "memory");
}

// One block = 4 waves = TWO independent 16-batch chains (P,Q) interleaved at
// half-step offset in the SAME instruction stream: while P's h-exchange
// (barrier + ds_read + MFMA) stalls, Q's cell math issues, and vice versa.
// Wall time = 256 x superstep, one superstep advances BOTH chains one step.
__global__ __launch_bounds__(256)
void lstm_fused(const float* __restrict__ x, const float* __restrict__ y,
                const float* __restrict__ Wih_e, const float* __restrict__ Whh_e,
                const float* __restrict__ b_e,
                const float* __restrict__ Wih_d, const float* __restrict__ Whh_d,
                const float* __restrict__ b_d,
                const float* __restrict__ Wfc, const float* __restrict__ bfc,
                float* __restrict__ out)
{
  const int tid  = threadIdx.x;
  const int lane = tid & 63;
  const int wv   = tid >> 6;      // 0..3
  const int lc   = lane & 15;     // batch within 16-tile (A-row / D-col n)
  const int lg   = lane >> 4;     // k-group / m-group
  const int b0P  = blockIdx.x * 32;
  const int b0Q  = b0P + 16;
  const int j    = 16*wv + lc;    // hidden unit this lane owns in cell update

  // h per chain: [chain][buf][16 batches][64 units] bf16, XOR-swizzled 16B
  // granules: elem (b,u) at b*64 + ((u>>3)^(b&7))*8 + (u&7).
  // Encoder: single buffer per chain (reads/writes always barrier-separated).
  // Decoder: double-buffered.
  __shared__ __align__(16) unsigned short hsm[2][2][16][64];
  __shared__ float red[2][2][4][16];
  unsigned short* hP = &hsm[0][0][0][0];
  unsigned short* hQ = &hsm[1][0][0][0];
  for (int idx = tid; idx < 2*2*16*64; idx += 256) (&hsm[0][0][0][0])[idx] = 0;

  const int rof0 = lc*64 + ((lg     ^ (lc&7)))*8;  // A-frag units lg*8..+7
  const int rof1 = lc*64 + (((4+lg) ^ (lc&7)))*8;  // units 32+lg*8..+7
  int wof[4];
  #pragma unroll
  for (int g = 0; g < 4; ++g) {
    const int b = lg*4 + g;
    wof[g] = b*64 + (((j>>3) ^ (b&7))*8) + (j&7);
  }

  // ---- encoder weight fragments (shared by both chains) ----
  short8 Bh[4][2], Bx[4];
  float bias[4];
  #pragma unroll
  for (int i = 0; i < 4; ++i) {
    const int r = 64*i + j;
    #pragma unroll
    for (int f = 0; f < 2; ++f) {
      S8U v;
      #pragma unroll
      for (int e2 = 0; e2 < 4; ++e2)
        v.u[e2] = cvt_pk_bf16(Whh_e[r*HID + f*32 + lg*8 + 2*e2],
                              Whh_e[r*HID + f*32 + lg*8 + 2*e2 + 1]);
      Bh[i][f] = v.s;
    }
    S8U vx;
    #pragma unroll
    for (int e2 = 0; e2 < 4; ++e2) {
      const int k0 = lg*8 + 2*e2, k1 = k0 + 1;
      vx.u[e2] = cvt_pk_bf16(k0 < ISZ ? Wih_e[r*ISZ + k0] : 0.f,
                             k1 < ISZ ? Wih_e[r*ISZ + k1] : 0.f);
    }
    Bx[i] = vx.s;
    bias[i] = b_e[r];
  }

  // ---- per-chain x pipelines: ax[s] packed for step t; xf[s] f32 for t+2 ----
  const float* xrP = x + (size_t)(b0P + lc)*ISZ;
  const float* xrQ = x + (size_t)(b0Q + lc)*ISZ;
  S8U axP[2], axQ[2];
  float xfP[2][8], xfQ[2][8];
  #pragma unroll
  for (int s = 0; s < 2; ++s) {
    float tp[8], tq[8];
    #pragma unroll
    for (int e = 0; e < 8; ++e) {
      const int k = lg*8 + e;
      tp[e] = (k < ISZ) ? xrP[(size_t)s*BATCH*ISZ + k] : 0.f;
      tq[e] = (k < ISZ) ? xrQ[(size_t)s*BATCH*ISZ + k] : 0.f;
      xfP[s][e] = 0.f; xfQ[s][e] = 0.f;
    }
    #pragma unroll
    for (int e2 = 0; e2 < 4; ++e2) {
      axP[s].u[e2] = cvt_pk_bf16(tp[2*e2], tp[2*e2+1]);
      axQ[s].u[e2] = cvt_pk_bf16(tq[2*e2], tq[2*e2+1]);
    }
  }
  #pragma unroll
  for (int s = 0; s < 2; ++s)
    #pragma unroll
    for (int e = 0; e < 8; ++e) {
      const int k = lg*8 + e;
      if (k < ISZ) { xfP[s][e] = xrP[(size_t)(2+s)*BATCH*ISZ + k];
                     xfQ[s][e] = xrQ[(size_t)(2+s)*BATCH*ISZ + k]; }
    }
  const float* xnP = xrP + (size_t)4*BATCH*ISZ;
  const float* xnQ = xrQ + (size_t)4*BATCH*ISZ;

  float cP[4] = {0.f,0.f,0.f,0.f}, cQ[4] = {0.f,0.f,0.f,0.f};
  f32x4 accP[4], accQ[4];
  __syncthreads();  // zero-init visible (one-time full drain ok)

#define CELL(ACC, C, DST) do { \
    float hn_[4]; \
    _Pragma("unroll") \
    for (int g = 0; g < 4; ++g) { \
      const float ig = sigm (ACC[0][g]); \
      const float fg = sigm (ACC[1][g]); \
      const float gg = tanha(ACC[2][g]); \
      const float og = sigm (ACC[3][g]); \
      const float cn = fg*C[g] + ig*gg; \
      C[g] = cn; \
      hn_[g] = og*tanha(cn); \
    } \
    const uint32_t w01 = cvt_pk_bf16(hn_[0], hn_[1]); \
    const uint32_t w23 = cvt_pk_bf16(hn_[2], hn_[3]); \
    (DST)[wof[0]] = (unsigned short)(w01 & 0xffffu); \
    (DST)[wof[1]] = (unsigned short)(w01 >> 16); \
    (DST)[wof[2]] = (unsigned short)(w23 & 0xffffu); \
    (DST)[wof[3]] = (unsigned short)(w23 >> 16); \
  } while (0)

  // prologue: accP = bias + x_P(0)  (h(0)=0 contributes nothing)
  #pragma unroll
  for (int i = 0; i < 4; ++i) {
    f32x4 a = {bias[i], bias[i], bias[i], bias[i]};
    accP[i] = __builtin_amdgcn_mfma_f32_16x16x32_bf16(axP[0].s, Bx[i], a, 0, 0, 0);
  }

  #pragma unroll 2
  for (int t = 0; t < T_STEPS; ++t) {
    const int s = t & 1;
    // ================= segment A =================
    lds_barrier();
    short8 aP0 = *(const short8*)(hP + rof0);
    short8 aP1 = *(const short8*)(hP + rof1);
    if (t) CELL(accQ, cQ, hQ);                 // cell_Q(t-1) -> h_Q(t)
    // Q x-init for step t (independent of h_Q)
    #pragma unroll
    for (int i = 0; i < 4; ++i) {
      f32x4 a = {bias[i], bias[i], bias[i], bias[i]};
      accQ[i] = __builtin_amdgcn_mfma_f32_16x16x32_bf16(axQ[s].s, Bx[i], a, 0, 0, 0);
    }
    // Q x-pipeline maintenance
    {
      S8U aqn;
      #pragma unroll
      for (int e2 = 0; e2 < 4; ++e2) aqn.u[e2] = cvt_pk_bf16(xfQ[s][2*e2], xfQ[s][2*e2+1]);
      if (t + 4 < T_STEPS) {
        #pragma unroll
        for (int e = 0; e < 8; ++e) { const int k = lg*8 + e; if (k < ISZ) xfQ[s][e] = xnQ[k]; }
      }
      axQ[s] = aqn; xnQ += BATCH*ISZ;
    }
    // P h-MFMAs (depth 2; ds_read latency hidden under Q work above)
    #pragma unroll
    for (int i = 0; i < 4; ++i)
      accP[i] = __builtin_amdgcn_mfma_f32_16x16x32_bf16(aP0, Bh[i][0], accP[i], 0, 0, 0);
    #pragma unroll
    for (int i = 0; i < 4; ++i)
      accP[i] = __builtin_amdgcn_mfma_f32_16x16x32_bf16(aP1, Bh[i][1], accP[i], 0, 0, 0);

    // ================= segment B =================
    lds_barrier();
    short8 aQ0 = *(const short8*)(hQ + rof0);
    short8 aQ1 = *(const short8*)(hQ + rof1);
    CELL(accP, cP, hP);                        // cell_P(t) -> h_P(t+1)
    // P x-init for step t+1
    #pragma unroll
    for (int i = 0; i < 4; ++i) {
      f32x4 a = {bias[i], bias[i], bias[i], bias[i]};
      accP[i] = __builtin_amdgcn_mfma_f32_16x16x32_bf16(axP[s^1].s, Bx[i], a, 0, 0, 0);
    }
    // P x-pipeline maintenance
    {
      S8U apn;
      #pragma unroll
      for (int e2 = 0; e2 < 4; ++e2) apn.u[e2] = cvt_pk_bf16(xfP[s][2*e2], xfP[s][2*e2+1]);
      if (t + 4 < T_STEPS) {
        #pragma unroll
        for (int e = 0; e < 8; ++e) { const int k = lg*8 + e; if (k < ISZ) xfP[s][e] = xnP[k]; }
      }
      axP[s] = apn; xnP += BATCH*ISZ;
    }
    // Q h-MFMAs
    #pragma unroll
    for (int i = 0; i < 4; ++i)
      accQ[i] = __builtin_amdgcn_mfma_f32_16x16x32_bf16(aQ0, Bh[i][0], accQ[i], 0, 0, 0);
    #pragma unroll
    for (int i = 0; i < 4; ++i)
      accQ[i] = __builtin_amdgcn_mfma_f32_16x16x32_bf16(aQ1, Bh[i][1], accQ[i], 0, 0, 0);
  }
  lds_barrier();             // protect segB(255) h_Q reads from epilogue write
  CELL(accQ, cQ, hQ);        // cell_Q(255) -> h_Q final

  // ---- decoder weights (overwrite Bh; global loads fill pre-barrier time) ----
  #pragma unroll
  for (int i = 0; i < 4; ++i) {
    const int r = 64*i + j;
    #pragma unroll
    for (int f = 0; f < 2; ++f) {
      S8U v;
      #pragma unroll
      for (int e2 = 0; e2 < 4; ++e2)
        v.u[e2] = cvt_pk_bf16(Whh_d[r*HID + f*32 + lg*8 + 2*e2],
                              Whh_d[r*HID + f*32 + lg*8 + 2*e2 + 1]);
      Bh[i][f] = v.s;
    }
  }
  float wd[4], bd[4], yvP[4], yvQ[4];
  #pragma unroll
  for (int i = 0; i < 4; ++i) { const int r = 64*i + j; wd[i] = Wih_d[r]; bd[i] = b_d[r]; }
  #pragma unroll
  for (int g = 0; g < 4; ++g) { yvP[g] = y[b0P + lg*4 + g]; yvQ[g] = y[b0Q + lg*4 + g]; }
  const float wfc = Wfc[j];
  const float bfv = bfc[0];

  // ---- decoder: both chains interleaved, double-buffered h ----
  for (int p = 0; p < PHOR; ++p) {
    const int pb = p & 1;
    lds_barrier();
    const unsigned short* rPb = hP + pb*1024;
    const unsigned short* rQb = hQ + pb*1024;
    unsigned short* wPb = hP + (pb^1)*1024;
    unsigned short* wQb = hQ + (pb^1)*1024;
    short8 aP0 = *(const short8*)(rPb + rof0);
    short8 aP1 = *(const short8*)(rPb + rof1);
    short8 aQ0 = *(const short8*)(rQb + rof0);
    short8 aQ1 = *(const short8*)(rQb + rof1);
    f32x4 dP[4], dQ[4];
    #pragma unroll
    for (int i = 0; i < 4; ++i) {
      f32x4 aP = {yvP[0]*wd[i]+bd[i], yvP[1]*wd[i]+bd[i], yvP[2]*wd[i]+bd[i], yvP[3]*wd[i]+bd[i]};
      f32x4 aQ = {yvQ[0]*wd[i]+bd[i], yvQ[1]*wd[i]+bd[i], yvQ[2]*wd[i]+bd[i], yvQ[3]*wd[i]+bd[i]};
      aP = __builtin_amdgcn_mfma_f32_16x16x32_bf16(aP0, Bh[i][0], aP, 0, 0, 0);
      dP[i] = __builtin_amdgcn_mfma_f32_16x16x32_bf16(aP1, Bh[i][1], aP, 0, 0, 0);
      aQ = __builtin_amdgcn_mfma_f32_16x16x32_bf16(aQ0, Bh[i][0], aQ, 0, 0, 0);
      dQ[i] = __builtin_amdgcn_mfma_f32_16x16x32_bf16(aQ1, Bh[i][1], aQ, 0, 0, 0);
    }
    float partP[4], partQ[4];
    {
      float hnP[4], hnQ[4];
      #pragma unroll
      for (int g = 0; g < 4; ++g) {
        float ig = sigm(dP[0][g]), fg = sigm(dP[1][g]), gg = tanha(dP[2][g]), og = sigm(dP[3][g]);
        float cn = fg*cP[g] + ig*gg; cP[g] = cn; hnP[g] = og*tanha(cn); partP[g] = hnP[g]*wfc;
        ig = sigm(dQ[0][g]); fg = sigm(dQ[1][g]); gg = tanha(dQ[2][g]); og = sigm(dQ[3][g]);
        cn = fg*cQ[g] + ig*gg; cQ[g] = cn; hnQ[g] = og*tanha(cn); partQ[g] = hnQ[g]*wfc;
      }
      const uint32_t p01 = cvt_pk_bf16(hnP[0], hnP[1]);
      const uint32_t p23 = cvt_pk_bf16(hnP[2], hnP[3]);
      wPb[wof[0]] = (unsigned short)(p01 & 0xffffu);
      wPb[wof[1]] = (unsigned short)(p01 >> 16);
      wPb[wof[2]] = (unsigned short)(p23 & 0xffffu);
      wPb[wof[3]] = (unsigned short)(p23 >> 16);
      const uint32_t q01 = cvt_pk_bf16(hnQ[0], hnQ[1]);
      const uint32_t q23 = cvt_pk_bf16(hnQ[2], hnQ[3]);
      wQb[wof[0]] = (unsigned short)(q01 & 0xffffu);
      wQb[wof[1]] = (unsigned short)(q01 >> 16);
      wQb[wof[2]] = (unsigned short)(q23 & 0xffffu);
      wQb[wof[3]] = (unsigned short)(q23 >> 16);
    }
    #pragma unroll
    for (int m = 1; m <= 8; m <<= 1) {
      #pragma unroll
      for (int g = 0; g < 4; ++g) {
        partP[g] += __shfl_xor(partP[g], m, 64);
        partQ[g] += __shfl_xor(partQ[g], m, 64);
      }
    }
    if (lc == 0) {
      #pragma unroll
      for (int g = 0; g < 4; ++g) {
        red[0][pb][wv][lg*4+g] = partP[g];
        red[1][pb][wv][lg*4+g] = partQ[g];
      }
    }
    lds_barrier();
    if (wv == 0 && lane < 16)
      out[(size_t)p*BATCH + b0P + lane] = bfv + red[0][pb][0][lane] + red[0][pb][1][lane]
                                              + red[0][pb][2][lane] + red[0][pb][3][lane];
    if (wv == 1 && lane < 16)
      out[(size_t)p*BATCH + b0Q + lane] = bfv + red[1][pb][0][lane] + red[1][pb][1][lane]
                                              + red[1][pb][2][lane] + red[1][pb][3][lane];
  }
#undef CELL
}

extern "C" void kernel_launch(void* const* d_in, const int* in_sizes, int n_in,
                              void* d_out, int out_size, void* d_ws, size_t ws_size,
                              hipStream_t stream) {
  const float* x     = (const float*)d_in[0];
  const float* y     = (const float*)d_in[1];
  // d_in[2] = teacher_force (0 in setup; inference branch only)
  const float* Wih_e = (const float*)d_in[3];
  const float* Whh_e = (const float*)d_in[4];
  const float* b_e   = (const float*)d_in[5];
  const float* Wih_d = (const float*)d_in[6];
  const float* Whh_d = (const float*)d_in[7];
  const float* b_d   = (const float*)d_in[8];
  const float* Wfc   = (const float*)d_in[9];
  const float* bfc   = (const float*)d_in[10];
  float* out = (float*)d_out;

  lstm_fused<<<dim3(BATCH/32), dim3(256), 0, stream>>>(
      x, y, Wih_e, Whh_e, b_e, Wih_d, Whh_d, b_d, Wfc, bfc, out);
}

// Round 5
// 169.828 us; speedup vs baseline: 2.0475x; 2.0475x over previous
//
#include <hip/hip_runtime.h>
#include <stdint.h>

#define T_STEPS 256
#define BATCH   2048
#define ISZ     11
#define HID     64
#define PHOR    12
#define BPB     8     // batches per block -> 256 blocks = 1 per CU

typedef __attribute__((ext_vector_type(8))) short short8;
typedef __attribute__((ext_vector_type(4))) float f32x4;

union S8U { short8 s; uint32_t u[4]; };
union FU  { float f; int i; };

__device__ __forceinline__ uint32_t cvt_pk_bf16(float lo, float hi) {
  uint32_t r;
  asm("v_cvt_pk_bf16_f32 %0, %1, %2" : "=v"(r) : "v"(lo), "v"(hi));
  return r;
}
// sigmoid with pre-scaled input: z = -log2(e)*v  ->  sigm = 1/(1+2^z)
__device__ __forceinline__ float sigm_z(float z) {
  return __builtin_amdgcn_rcpf(1.0f + __builtin_amdgcn_exp2f(z));
}
__device__ __forceinline__ float bperm_f(int idx4, float v) {
  FU a; a.f = v;
  FU r; r.i = __builtin_amdgcn_ds_bpermute(idx4, a.i);
  return r.f;
}
// Barrier draining LDS only — global loads stay in flight (no vmcnt(0)).
__device__ __forceinline__ void lds_barrier() {
  asm volatile("s_waitcnt lgkmcnt(0)" ::: "memory");
  __builtin_amdgcn_s_barrier();
  asm volatile("" ::: "memory");
}

// 1 chain of 8 batches per block, 256 blocks = 1/CU. 4 waves; wave wv owns
// hidden units 16wv..16wv+15 (gate tiles {wv,4+wv,8+wv,12+wv}). MFMA m=16
// with 8 real batch rows; gate outputs redistributed via ds_bpermute so all
// 64 lanes carry 2 cell elements. Weights pre-scaled by -log2e (sigm gates)
// and -2log2e (tanh gate) to make activations exp2+rcp only.
__global__ __launch_bounds__(256)
void lstm_fused(const float* __restrict__ x, const float* __restrict__ y,
                const float* __restrict__ Wih_e, const float* __restrict__ Whh_e,
                const float* __restrict__ b_e,
                const float* __restrict__ Wih_d, const float* __restrict__ Whh_d,
                const float* __restrict__ b_d,
                const float* __restrict__ Wfc, const float* __restrict__ bfc,
                float* __restrict__ out)
{
  const int tid  = threadIdx.x;
  const int lane = tid & 63;
  const int wv   = tid >> 6;      // 0..3
  const int lc   = lane & 15;     // A-row (batch) / D-col (unit) within tile
  const int lg   = lane >> 4;     // k-group / m-group
  const int b0   = blockIdx.x * BPB;
  const int j    = 16*wv + lc;    // hidden unit this lane owns
  const bool low = (lg < 2);      // lanes keeping local regs 0,1
  const int bpidx = (lane & 31) << 2;             // pull from lane-32 (lanes>=32)
  const int bmA  = ((lg & 1) << 2) | (lg & 2);    // 0,4,2,6 per lg
  const int bmB  = bmA + 1;

  // h: [buf][16 rows (8 real)][64 units] bf16, XOR-swizzled 16B granules:
  // elem (b,u) at b*64 + ((u>>3)^(b&7))*8 + (u&7). Rows 8-15 stay zero.
  __shared__ __align__(16) unsigned short hsm[2][16][64];
  __shared__ float red[2][4][BPB];
  unsigned short* hb = &hsm[0][0][0];
  for (int idx = tid; idx < 2*16*64; idx += 256) hb[idx] = 0;

  const int rof0 = lc*64 + ((lg     ^ (lc&7)))*8;  // A-frag units lg*8..+7
  const int rof1 = lc*64 + (((4+lg) ^ (lc&7)))*8;  // units 32+lg*8..+7
  const int wofA = bmA*64 + (((j>>3) ^ (bmA&7))*8) + (j&7);
  const int wofB = bmB*64 + (((j>>3) ^ (bmB&7))*8) + (j&7);

  // gate scales: PyTorch order i,f,g,o — sigm: -log2e, tanh: -2log2e
  const float SC[4] = {-1.44269504f, -1.44269504f, -2.88539008f, -1.44269504f};

  // ---- encoder weight fragments (prescaled, persistent in VGPRs) ----
  short8 Bh[4][2], Bx[4];
  float bias[4];
  #pragma unroll
  for (int i = 0; i < 4; ++i) {
    const int r = 64*i + j;
    const float s = SC[i];
    #pragma unroll
    for (int f = 0; f < 2; ++f) {
      S8U v;
      #pragma unroll
      for (int e2 = 0; e2 < 4; ++e2)
        v.u[e2] = cvt_pk_bf16(Whh_e[r*HID + f*32 + lg*8 + 2*e2]*s,
                              Whh_e[r*HID + f*32 + lg*8 + 2*e2 + 1]*s);
      Bh[i][f] = v.s;
    }
    S8U vx;
    #pragma unroll
    for (int e2 = 0; e2 < 4; ++e2) {
      const int k0 = lg*8 + 2*e2, k1 = k0 + 1;
      vx.u[e2] = cvt_pk_bf16(k0 < ISZ ? Wih_e[r*ISZ + k0]*s : 0.f,
                             k1 < ISZ ? Wih_e[r*ISZ + k1]*s : 0.f);
    }
    Bx[i] = vx.s;
    bias[i] = b_e[r]*s;
  }

  // ---- x pipeline (rows clamped to real batches; pad rows harmless) ----
  const float* xrow = x + (size_t)(b0 + (lc & 7))*ISZ;
  float xf[2][8];
  S8U ax[2];
  #pragma unroll
  for (int s = 0; s < 2; ++s) {
    float tmp[8];
    #pragma unroll
    for (int e = 0; e < 8; ++e) {
      const int k = lg*8 + e;
      tmp[e] = (k < ISZ) ? xrow[(size_t)s*BATCH*ISZ + k] : 0.f;
      xf[s][e] = 0.f;
    }
    #pragma unroll
    for (int e2 = 0; e2 < 4; ++e2) ax[s].u[e2] = cvt_pk_bf16(tmp[2*e2], tmp[2*e2+1]);
  }
  #pragma unroll
  for (int s = 0; s < 2; ++s)
    #pragma unroll
    for (int e = 0; e < 8; ++e) {
      const int k = lg*8 + e;
      if (k < ISZ) xf[s][e] = xrow[(size_t)(2+s)*BATCH*ISZ + k];
    }
  const float* xnl = xrow + (size_t)4*BATCH*ISZ;

  float cA = 0.f, cB = 0.f;    // cell state for the 2 redistributed elements
  __syncthreads();             // zero-init visible

  // ---- encoder recurrence: 1 barrier/step, double-buffered h ----
  #pragma unroll 2
  for (int t = 0; t < T_STEPS; ++t) {
    const int s = t & 1;
    const unsigned short* hr = hb + s*1024;
    unsigned short*       hw = hb + (s^1)*1024;
    short8 ah0 = *(const short8*)(hr + rof0);
    short8 ah1 = *(const short8*)(hr + rof1);

    f32x4 acc[4];
    #pragma unroll
    for (int i = 0; i < 4; ++i) {
      f32x4 a = {bias[i], bias[i], bias[i], bias[i]};
      acc[i] = __builtin_amdgcn_mfma_f32_16x16x32_bf16(ax[s].s, Bx[i], a, 0, 0, 0);
    }
    // pipeline maintenance in the ds_read/MFMA shadow
    S8U axn;
    #pragma unroll
    for (int e2 = 0; e2 < 4; ++e2) axn.u[e2] = cvt_pk_bf16(xf[s][2*e2], xf[s][2*e2+1]);
    if (t + 4 < T_STEPS) {
      #pragma unroll
      for (int e = 0; e < 8; ++e) { const int k = lg*8 + e; if (k < ISZ) xf[s][e] = xnl[k]; }
    }
    #pragma unroll
    for (int i = 0; i < 4; ++i)
      acc[i] = __builtin_amdgcn_mfma_f32_16x16x32_bf16(ah0, Bh[i][0], acc[i], 0, 0, 0);
    #pragma unroll
    for (int i = 0; i < 4; ++i)
      acc[i] = __builtin_amdgcn_mfma_f32_16x16x32_bf16(ah1, Bh[i][1], acc[i], 0, 0, 0);
    ax[s] = axn;
    xnl += BATCH*ISZ;

    // redistribute: every lane ends with 2 elements (gates zA/zB per tile)
    float gA[4], gB[4];
    #pragma unroll
    for (int i = 0; i < 4; ++i) {
      const float pA = bperm_f(bpidx, acc[i][2]);
      const float pB = bperm_f(bpidx, acc[i][3]);
      gA[i] = low ? acc[i][0] : pA;
      gB[i] = low ? acc[i][1] : pB;
    }
    // cell (pre-scaled z): sigm = rcp(1+exp2(z)); tanh = 2*rcp(1+exp2(z))-1
    const float iA = sigm_z(gA[0]), fA = sigm_z(gA[1]), oA = sigm_z(gA[3]);
    const float iB = sigm_z(gB[0]), fB = sigm_z(gB[1]), oB = sigm_z(gB[3]);
    const float ggA = 2.f*sigm_z(gA[2]) - 1.f;
    const float ggB = 2.f*sigm_z(gB[2]) - 1.f;
    cA = fA*cA + iA*ggA;
    cB = fB*cB + iB*ggB;
    const float thA = 2.f*sigm_z(cA * -2.88539008f) - 1.f;
    const float thB = 2.f*sigm_z(cB * -2.88539008f) - 1.f;
    const float hA = oA*thA, hB = oB*thB;

    const uint32_t pk = cvt_pk_bf16(hA, hB);
    hw[wofA] = (unsigned short)(pk & 0xffffu);
    hw[wofB] = (unsigned short)(pk >> 16);
    lds_barrier();
  }

  // ---- decoder weights (prescaled) ----
  #pragma unroll
  for (int i = 0; i < 4; ++i) {
    const int r = 64*i + j;
    const float s = SC[i];
    #pragma unroll
    for (int f = 0; f < 2; ++f) {
      S8U v;
      #pragma unroll
      for (int e2 = 0; e2 < 4; ++e2)
        v.u[e2] = cvt_pk_bf16(Whh_d[r*HID + f*32 + lg*8 + 2*e2]*s,
                              Whh_d[r*HID + f*32 + lg*8 + 2*e2 + 1]*s);
      Bh[i][f] = v.s;
    }
  }
  f32x4 gi[4];
  {
    float yv[4];
    #pragma unroll
    for (int r = 0; r < 4; ++r) {
      const int m = lg*4 + r;
      yv[r] = (m < BPB) ? y[b0 + m] : 0.f;
    }
    #pragma unroll
    for (int i = 0; i < 4; ++i) {
      const int r = 64*i + j;
      const float wd = Wih_d[r]*SC[i], bd = b_d[r]*SC[i];
      #pragma unroll
      for (int g = 0; g < 4; ++g) gi[i][g] = yv[g]*wd + bd;
    }
  }
  const float wfc = Wfc[j];
  const float bfv = bfc[0];

  // ---- decoder: 1 barrier/step; h and red double-buffered ----
  for (int p = 0; p < PHOR; ++p) {
    const int pb = p & 1;
    const unsigned short* hr = hb + pb*1024;
    unsigned short*       hw = hb + (pb^1)*1024;
    short8 ah0 = *(const short8*)(hr + rof0);
    short8 ah1 = *(const short8*)(hr + rof1);
    f32x4 acc[4];
    #pragma unroll
    for (int i = 0; i < 4; ++i) {
      f32x4 a = __builtin_amdgcn_mfma_f32_16x16x32_bf16(ah0, Bh[i][0], gi[i], 0, 0, 0);
      acc[i] = __builtin_amdgcn_mfma_f32_16x16x32_bf16(ah1, Bh[i][1], a, 0, 0, 0);
    }
    float gA[4], gB[4];
    #pragma unroll
    for (int i = 0; i < 4; ++i) {
      const float pA = bperm_f(bpidx, acc[i][2]);
      const float pB = bperm_f(bpidx, acc[i][3]);
      gA[i] = low ? acc[i][0] : pA;
      gB[i] = low ? acc[i][1] : pB;
    }
    const float iA = sigm_z(gA[0]), fA = sigm_z(gA[1]), oA = sigm_z(gA[3]);
    const float iB = sigm_z(gB[0]), fB = sigm_z(gB[1]), oB = sigm_z(gB[3]);
    const float ggA = 2.f*sigm_z(gA[2]) - 1.f;
    const float ggB = 2.f*sigm_z(gB[2]) - 1.f;
    cA = fA*cA + iA*ggA;
    cB = fB*cB + iB*ggB;
    const float thA = 2.f*sigm_z(cA * -2.88539008f) - 1.f;
    const float thB = 2.f*sigm_z(cB * -2.88539008f) - 1.f;
    const float hA = oA*thA, hB = oB*thB;

    const uint32_t pk = cvt_pk_bf16(hA, hB);
    hw[wofA] = (unsigned short)(pk & 0xffffu);
    hw[wofB] = (unsigned short)(pk >> 16);

    float partA = hA * wfc, partB = hB * wfc;
    #pragma unroll
    for (int m = 1; m <= 8; m <<= 1) {
      partA += __shfl_xor(partA, m, 64);
      partB += __shfl_xor(partB, m, 64);
    }
    if (lc == 0) {
      red[pb][wv][bmA] = partA;
      red[pb][wv][bmB] = partB;
    }
    lds_barrier();
    if (tid < BPB)
      out[(size_t)p*BATCH + b0 + tid] = bfv + red[pb][0][tid] + red[pb][1][tid]
                                            + red[pb][2][tid] + red[pb][3][tid];
  }
}

extern "C" void kernel_launch(void* const* d_in, const int* in_sizes, int n_in,
                              void* d_out, int out_size, void* d_ws, size_t ws_size,
                              hipStream_t stream) {
  const float* x     = (const float*)d_in[0];
  const float* y     = (const float*)d_in[1];
  // d_in[2] = teacher_force (0 in setup; inference branch only)
  const float* Wih_e = (const float*)d_in[3];
  const float* Whh_e = (const float*)d_in[4];
  const float* b_e   = (const float*)d_in[5];
  const float* Wih_d = (const float*)d_in[6];
  const float* Whh_d = (const float*)d_in[7];
  const float* b_d   = (const float*)d_in[8];
  const float* Wfc   = (const float*)d_in[9];
  const float* bfc   = (const float*)d_in[10];
  float* out = (float*)d_out;

  lstm_fused<<<dim3(BATCH/BPB), dim3(256), 0, stream>>>(
      x, y, Wih_e, Whh_e, b_e, Wih_d, Whh_d, b_d, Wfc, bfc, out);
}

// Round 6
// 168.111 us; speedup vs baseline: 2.0684x; 1.0102x over previous
//
#include <hip/hip_runtime.h>
#include <stdint.h>

#define T_STEPS 256
#define BATCH   2048
#define ISZ     11
#define HID     64
#define PHOR    12
#define BPB     8     // batches per block -> 256 blocks = 1 per CU

typedef __attribute__((ext_vector_type(8))) short short8;
typedef __attribute__((ext_vector_type(4))) float f32x4;

union S8U { short8 s; uint32_t u[4]; };

__device__ __forceinline__ uint32_t cvt_pk_bf16(float lo, float hi) {
  uint32_t r;
  asm("v_cvt_pk_bf16_f32 %0, %1, %2" : "=v"(r) : "v"(lo), "v"(hi));
  return r;
}
// sigmoid with pre-scaled input: z = -log2(e)*v  ->  sigm = 1/(1+2^z)
__device__ __forceinline__ float sigm_z(float z) {
  return __builtin_amdgcn_rcpf(1.0f + __builtin_amdgcn_exp2f(z));
}
// D0.hi <-> D1.lo half-wave swap: after call, a[l<32]=a, a[l>=32]=b[l-32].
__device__ __forceinline__ float permswap(float a, float b) {
  asm("v_permlane32_swap_b32 %0, %1" : "+v"(a), "+v"(b));
  return a;
}
// Barrier draining LDS only — global loads stay in flight (no vmcnt(0)).
__device__ __forceinline__ void lds_barrier() {
  asm volatile("s_waitcnt lgkmcnt(0)" ::: "memory");
  __builtin_amdgcn_s_barrier();
  asm volatile("" ::: "memory");
}

// 1 chain of 8 batches per block, 256 blocks = 1/CU. Wave wv owns hidden
// units 16wv..16wv+15 (gate tiles {wv,4+wv,8+wv,12+wv}). Gate outputs
// redistributed via v_permlane32_swap (VALU, no LDS) so all 64 lanes carry
// 2 cell elements. Weights pre-scaled by -log2e / -2log2e so activations
// are exp2+rcp only. Critical path per step: barrier -> ds_read -> 1 MFMA
// (+add) -> permswap -> cell -> write; x-MFMA of the NEXT step issues
// pre-barrier into its own accumulator.
__global__ __launch_bounds__(256)
void lstm_fused(const float* __restrict__ x, const float* __restrict__ y,
                const float* __restrict__ Wih_e, const float* __restrict__ Whh_e,
                const float* __restrict__ b_e,
                const float* __restrict__ Wih_d, const float* __restrict__ Whh_d,
                const float* __restrict__ b_d,
                const float* __restrict__ Wfc, const float* __restrict__ bfc,
                float* __restrict__ out)
{
  const int tid  = threadIdx.x;
  const int lane = tid & 63;
  const int wv   = tid >> 6;      // 0..3
  const int lc   = lane & 15;     // A-row (batch) / D-col (unit) within tile
  const int lg   = lane >> 4;     // k-group / m-group
  const int b0   = blockIdx.x * BPB;
  const int j    = 16*wv + lc;    // hidden unit this lane owns
  const int bmA  = ((lg & 1) << 2) | (lg & 2);    // 0,4,2,6 per lg
  const int bmB  = bmA + 1;

  // h: [buf][16 rows (8 real)][64 units] bf16, XOR-swizzled 16B granules:
  // elem (b,u) at b*64 + ((u>>3)^(b&7))*8 + (u&7). Rows 8-15 stay zero.
  __shared__ __align__(16) unsigned short hsm[2][16][64];
  __shared__ float red[2][4][BPB];
  unsigned short* hb = &hsm[0][0][0];
  for (int idx = tid; idx < 2*16*64; idx += 256) hb[idx] = 0;

  const int rof0 = lc*64 + ((lg     ^ (lc&7)))*8;  // A-frag units lg*8..+7
  const int rof1 = lc*64 + (((4+lg) ^ (lc&7)))*8;  // units 32+lg*8..+7
  const int wofA = bmA*64 + (((j>>3) ^ (bmA&7))*8) + (j&7);
  const int wofB = bmB*64 + (((j>>3) ^ (bmB&7))*8) + (j&7);

  // gate scales: PyTorch order i,f,g,o — sigm: -log2e, tanh: -2log2e
  const float SC[4] = {-1.44269504f, -1.44269504f, -2.88539008f, -1.44269504f};

  // ---- encoder weight fragments (prescaled, persistent in VGPRs) ----
  short8 Bh[4][2], Bx[4];
  float bias[4];
  #pragma unroll
  for (int i = 0; i < 4; ++i) {
    const int r = 64*i + j;
    const float s = SC[i];
    #pragma unroll
    for (int f = 0; f < 2; ++f) {
      S8U v;
      #pragma unroll
      for (int e2 = 0; e2 < 4; ++e2)
        v.u[e2] = cvt_pk_bf16(Whh_e[r*HID + f*32 + lg*8 + 2*e2]*s,
                              Whh_e[r*HID + f*32 + lg*8 + 2*e2 + 1]*s);
      Bh[i][f] = v.s;
    }
    S8U vx;
    #pragma unroll
    for (int e2 = 0; e2 < 4; ++e2) {
      const int k0 = lg*8 + 2*e2, k1 = k0 + 1;
      vx.u[e2] = cvt_pk_bf16(k0 < ISZ ? Wih_e[r*ISZ + k0]*s : 0.f,
                             k1 < ISZ ? Wih_e[r*ISZ + k1]*s : 0.f);
    }
    Bx[i] = vx.s;
    bias[i] = b_e[r]*s;
  }

  // ---- x pipeline (rows clamped to real batches; pad rows harmless) ----
  const float* xrow = x + (size_t)(b0 + (lc & 7))*ISZ;
  float xf[2][8];
  S8U ax[2];
  #pragma unroll
  for (int s = 0; s < 2; ++s) {
    float tmp[8];
    #pragma unroll
    for (int e = 0; e < 8; ++e) {
      const int k = lg*8 + e;
      tmp[e] = (k < ISZ) ? xrow[(size_t)s*BATCH*ISZ + k] : 0.f;
      xf[s][e] = 0.f;
    }
    #pragma unroll
    for (int e2 = 0; e2 < 4; ++e2) ax[s].u[e2] = cvt_pk_bf16(tmp[2*e2], tmp[2*e2+1]);
  }
  #pragma unroll
  for (int s = 0; s < 2; ++s)
    #pragma unroll
    for (int e = 0; e < 8; ++e) {
      const int k = lg*8 + e;
      if (k < ISZ) xf[s][e] = xrow[(size_t)(2+s)*BATCH*ISZ + k];
    }
  const float* xnl = xrow + (size_t)4*BATCH*ISZ;

  float cA = 0.f, cB = 0.f;
  const f32x4 vzero = {0.f, 0.f, 0.f, 0.f};

  // prologue: accx(0) = bias + x(0)-part (h(0)=0)
  f32x4 accx[4];
  #pragma unroll
  for (int i = 0; i < 4; ++i) {
    f32x4 a = {bias[i], bias[i], bias[i], bias[i]};
    accx[i] = __builtin_amdgcn_mfma_f32_16x16x32_bf16(ax[0].s, Bx[i], a, 0, 0, 0);
  }

  // ---- encoder recurrence: barrier at top, double-buffered h ----
  #pragma unroll 2
  for (int t = 0; t < T_STEPS; ++t) {
    const int s = t & 1;
    lds_barrier();                 // h(t) (and first-iter zero-init) visible
    const unsigned short* hr = hb + s*1024;
    unsigned short*       hw = hb + (s^1)*1024;
    short8 ah0 = *(const short8*)(hr + rof0);
    short8 ah1 = *(const short8*)(hr + rof1);

    f32x4 gacc[4];
    #pragma unroll
    for (int i = 0; i < 4; ++i) {
      f32x4 a = __builtin_amdgcn_mfma_f32_16x16x32_bf16(ah0, Bh[i][0], accx[i], 0, 0, 0);
      f32x4 b = __builtin_amdgcn_mfma_f32_16x16x32_bf16(ah1, Bh[i][1], vzero,   0, 0, 0);
      gacc[i] = a + b;
    }

    // redistribute via half-wave swap: every lane gets 2 cell elements
    float gA[4], gB[4];
    #pragma unroll
    for (int i = 0; i < 4; ++i) {
      gA[i] = permswap(gacc[i][0], gacc[i][2]);
      gB[i] = permswap(gacc[i][1], gacc[i][3]);
    }
    const float iA = sigm_z(gA[0]), fA = sigm_z(gA[1]), oA = sigm_z(gA[3]);
    const float iB = sigm_z(gB[0]), fB = sigm_z(gB[1]), oB = sigm_z(gB[3]);
    const float ggA = 2.f*sigm_z(gA[2]) - 1.f;
    const float ggB = 2.f*sigm_z(gB[2]) - 1.f;
    cA = fA*cA + iA*ggA;
    cB = fB*cB + iB*ggB;
    const float thA = 2.f*sigm_z(cA * -2.88539008f) - 1.f;
    const float thB = 2.f*sigm_z(cB * -2.88539008f) - 1.f;
    const float hA = oA*thA, hB = oB*thB;

    const uint32_t pk = cvt_pk_bf16(hA, hB);
    hw[wofA] = (unsigned short)(pk & 0xffffu);
    hw[wofB] = (unsigned short)(pk >> 16);

    // ---- pre-barrier work for step t+1 (fills barrier-arrival skew) ----
    #pragma unroll
    for (int i = 0; i < 4; ++i) {
      f32x4 a = {bias[i], bias[i], bias[i], bias[i]};
      accx[i] = __builtin_amdgcn_mfma_f32_16x16x32_bf16(ax[s^1].s, Bx[i], a, 0, 0, 0);
    }
    S8U axn;
    #pragma unroll
    for (int e2 = 0; e2 < 4; ++e2) axn.u[e2] = cvt_pk_bf16(xf[s][2*e2], xf[s][2*e2+1]);
    if (t + 4 < T_STEPS) {
      #pragma unroll
      for (int e = 0; e < 8; ++e) { const int k = lg*8 + e; if (k < ISZ) xf[s][e] = xnl[k]; }
    }
    ax[s] = axn;
    xnl += BATCH*ISZ;
  }

  // ---- decoder weights (prescaled) ----
  #pragma unroll
  for (int i = 0; i < 4; ++i) {
    const int r = 64*i + j;
    const float s = SC[i];
    #pragma unroll
    for (int f = 0; f < 2; ++f) {
      S8U v;
      #pragma unroll
      for (int e2 = 0; e2 < 4; ++e2)
        v.u[e2] = cvt_pk_bf16(Whh_d[r*HID + f*32 + lg*8 + 2*e2]*s,
                              Whh_d[r*HID + f*32 + lg*8 + 2*e2 + 1]*s);
      Bh[i][f] = v.s;
    }
  }
  f32x4 gi[4];
  {
    float yv[4];
    #pragma unroll
    for (int r = 0; r < 4; ++r) {
      const int m = lg*4 + r;
      yv[r] = (m < BPB) ? y[b0 + m] : 0.f;
    }
    #pragma unroll
    for (int i = 0; i < 4; ++i) {
      const int r = 64*i + j;
      const float wd = Wih_d[r]*SC[i], bd = b_d[r]*SC[i];
      #pragma unroll
      for (int g = 0; g < 4; ++g) gi[i][g] = yv[g]*wd + bd;
    }
  }
  const float wfc = Wfc[j];
  const float bfv = bfc[0];

  // ---- decoder: h(T) sits in buf0 (T even); 2 barriers/step (12 steps) ----
  for (int p = 0; p < PHOR; ++p) {
    const int pb = p & 1;
    lds_barrier();               // h(p) visible
    const unsigned short* hr = hb + pb*1024;
    unsigned short*       hw = hb + (pb^1)*1024;
    short8 ah0 = *(const short8*)(hr + rof0);
    short8 ah1 = *(const short8*)(hr + rof1);
    f32x4 gacc[4];
    #pragma unroll
    for (int i = 0; i < 4; ++i) {
      f32x4 a = __builtin_amdgcn_mfma_f32_16x16x32_bf16(ah0, Bh[i][0], gi[i], 0, 0, 0);
      f32x4 b = __builtin_amdgcn_mfma_f32_16x16x32_bf16(ah1, Bh[i][1], vzero, 0, 0, 0);
      gacc[i] = a + b;
    }
    float gA[4], gB[4];
    #pragma unroll
    for (int i = 0; i < 4; ++i) {
      gA[i] = permswap(gacc[i][0], gacc[i][2]);
      gB[i] = permswap(gacc[i][1], gacc[i][3]);
    }
    const float iA = sigm_z(gA[0]), fA = sigm_z(gA[1]), oA = sigm_z(gA[3]);
    const float iB = sigm_z(gB[0]), fB = sigm_z(gB[1]), oB = sigm_z(gB[3]);
    const float ggA = 2.f*sigm_z(gA[2]) - 1.f;
    const float ggB = 2.f*sigm_z(gB[2]) - 1.f;
    cA = fA*cA + iA*ggA;
    cB = fB*cB + iB*ggB;
    const float thA = 2.f*sigm_z(cA * -2.88539008f) - 1.f;
    const float thB = 2.f*sigm_z(cB * -2.88539008f) - 1.f;
    const float hA = oA*thA, hB = oB*thB;

    const uint32_t pk = cvt_pk_bf16(hA, hB);
    hw[wofA] = (unsigned short)(pk & 0xffffu);
    hw[wofB] = (unsigned short)(pk >> 16);

    float partA = hA * wfc, partB = hB * wfc;
    #pragma unroll
    for (int m = 1; m <= 8; m <<= 1) {
      partA += __shfl_xor(partA, m, 64);
      partB += __shfl_xor(partB, m, 64);
    }
    if (lc == 0) {
      red[pb][wv][bmA] = partA;
      red[pb][wv][bmB] = partB;
    }
    lds_barrier();               // red visible
    if (tid < BPB)
      out[(size_t)p*BATCH + b0 + tid] = bfv + red[pb][0][tid] + red[pb][1][tid]
                                            + red[pb][2][tid] + red[pb][3][tid];
  }
}

extern "C" void kernel_launch(void* const* d_in, const int* in_sizes, int n_in,
                              void* d_out, int out_size, void* d_ws, size_t ws_size,
                              hipStream_t stream) {
  const float* x     = (const float*)d_in[0];
  const float* y     = (const float*)d_in[1];
  // d_in[2] = teacher_force (0 in setup; inference branch only)
  const float* Wih_e = (const float*)d_in[3];
  const float* Whh_e = (const float*)d_in[4];
  const float* b_e   = (const float*)d_in[5];
  const float* Wih_d = (const float*)d_in[6];
  const float* Whh_d = (const float*)d_in[7];
  const float* b_d   = (const float*)d_in[8];
  const float* Wfc   = (const float*)d_in[9];
  const float* bfc   = (const float*)d_in[10];
  float* out = (float*)d_out;

  lstm_fused<<<dim3(BATCH/BPB), dim3(256), 0, stream>>>(
      x, y, Wih_e, Whh_e, b_e, Wih_d, Whh_d, b_d, Wfc, bfc, out);
}